// Round 1
// 97.112 us; speedup vs baseline: 1.0591x; 1.0591x over previous
//
#include <hip/hip_runtime.h>
#include <math.h>

// B=8, C=128, H=W=64, HW=4096, c8=16, c2=64, pooled J=1024
#define HW 4096
#define SHIFT 12.0f   // exact softmax invariant; folded into MFMA C-init (z16=-SHIFT)

typedef __attribute__((ext_vector_type(4)))  short short4v;
typedef __attribute__((ext_vector_type(8)))  short short8;
typedef __attribute__((ext_vector_type(2)))  int   int2v;
typedef __attribute__((ext_vector_type(4)))  int   int4v;
typedef __attribute__((ext_vector_type(4)))  float f32x4;
typedef __attribute__((ext_vector_type(16))) float f32x16;

#define MFMA16 __builtin_amdgcn_mfma_f32_16x16x32_bf16
#define MFMA32 __builtin_amdgcn_mfma_f32_32x32x16_bf16

__device__ inline short f2b(float f) {   // fp32 -> bf16 RNE (scalar fallback)
    union { float f; unsigned u; } v; v.f = f;
    unsigned r = v.u + 0x7fffu + ((v.u >> 16) & 1u);
    return (short)(r >> 16);
}
// HW packed convert: low16 = bf16(lo), high16 = bf16(hi). RNE == f2b bit-exact.
__device__ inline int cvtpk(float lo, float hi) {
    int r;
    asm("v_cvt_pk_bf16_f32 %0, %1, %2" : "=v"(r) : "v"(lo), "v"(hi));
    return r;
}
// dst.hi32lanes <-> src.lo32lanes exchange; replaces shfl_xor(32)+cndmask pairs
__device__ inline void plswap(int& a, int& b) {
    asm("v_permlane32_swap_b32 %0, %1" : "+v"(a), "+v"(b));
}
__device__ inline float max4(float a, float b, float c, float d) {
    return fmaxf(fmaxf(a, b), fmaxf(c, d));
}

// ---------------------------------------------------------------------------
// K0: one-time fp32 -> bf16 weight conversion.
// wb layout (shorts): [0,2048) wt, [2048,4096) wp, [4096,12288) wg,
// [12288,20480) wo. 20480 floats total; 20 blocks x 256 thr x 4 floats.
__global__ __launch_bounds__(256) void wconv(
    const float* __restrict__ wt, const float* __restrict__ wp,
    const float* __restrict__ wg, const float* __restrict__ wo,
    short* __restrict__ wb)
{
    int idx = (blockIdx.x * 256 + threadIdx.x) * 4;
    const float* src;
    if (idx < 2048)       src = wt + idx;
    else if (idx < 4096)  src = wp + (idx - 2048);
    else if (idx < 12288) src = wg + (idx - 4096);
    else                  src = wo + (idx - 12288);
    f32x4 v = *(const f32x4*)src;
    int2v o; o.x = cvtpk(v.x, v.y); o.y = cvtpk(v.z, v.w);
    *(int2v*)(wb + idx) = o;
}

// ---------------------------------------------------------------------------
// K1: fused 1x1 convs + 2x2 maxpool. Weights now pre-converted bf16 (K0).
// Block bid = (b, rp, h): rows {2rp,2rp+1}, cols [32h,32h+32) -> 64 px.
// x staged bf16 in LDS [128c][68]. Wave w: px-pair p=w&1, cs group (w>>1)*3.
__global__ __launch_bounds__(256) void conv_pool(
    const float* __restrict__ x, const short* __restrict__ wb,
    short* __restrict__ theta_t, short* __restrict__ phi_t,
    short* __restrict__ g_blk)
{
    __shared__ __align__(16) short xl[128 * 68];
    const int tid = threadIdx.x;
    const int w = tid >> 6, lane = tid & 63, l15 = lane & 15, lg = (lane >> 4) & 3;
    const int bid = blockIdx.x;
    const int b = bid >> 6, ri = bid & 63, rp = ri >> 1, h = ri & 1;
    const float* xb = x + (size_t)b * 128 * HW + rp * 128 + h * 32;

    for (int it = 0; it < 8; it++) {          // 2048 float4s
        int idx = it * 256 + tid;
        int c = idx >> 4, q = idx & 15;
        int px4 = q * 4, r = px4 >> 5, col4 = px4 & 31;
        f32x4 v = *(const f32x4*)(xb + (size_t)c * HW + r * 64 + col4);
        int2v sv; sv.x = cvtpk(v.x, v.y); sv.y = cvtpk(v.z, v.w);
        *(int2v*)(xl + c * 68 + px4) = sv;
    }
    __syncthreads();

    const int p = w & 1, csbase = (w >> 1) * 3;
    const short* wb_t = wb;            // [16][128]
    const short* wb_p = wb + 2048;     // [16][128]
    const short* wb_g = wb + 4096;     // [64][128]
    f32x4 acc[2][3];
#pragma unroll
    for (int cc = 0; cc < 2; cc++)
#pragma unroll
        for (int cl = 0; cl < 3; cl++) acc[cc][cl] = (f32x4){0.f, 0.f, 0.f, 0.f};

#pragma unroll
    for (int ks = 0; ks < 4; ks++) {
        short8 a[2];
#pragma unroll
        for (int cc = 0; cc < 2; cc++) {
            int px = (p + 2 * cc) * 16 + l15;
#pragma unroll
            for (int q = 0; q < 8; q++)
                a[cc][q] = xl[(ks * 32 + lg * 8 + q) * 68 + px];
        }
#pragma unroll
        for (int csl = 0; csl < 3; csl++) {
            int cs = csbase + csl;
            const short* wrow;
            if (cs == 0)      wrow = wb_t + l15 * 128;
            else if (cs == 1) wrow = wb_p + l15 * 128;
            else              wrow = wb_g + ((cs - 2) * 16 + l15) * 128;
            short8 bf = *(const short8*)(wrow + ks * 32 + lg * 8);
            acc[0][csl] = MFMA16(a[0], bf, acc[0][csl], 0, 0, 0);
            acc[1][csl] = MFMA16(a[1], bf, acc[1][csl], 0, 0, 0);
        }
    }

    const size_t pixb = (size_t)b * 4096 + rp * 128 + h * 32 + p * 16;
#pragma unroll
    for (int csl = 0; csl < 3; csl++) {
        int cs = csbase + csl;
        if (cs == 0) {            // theta: C rows = px-in-chunk
#pragma unroll
            for (int cc = 0; cc < 2; cc++)
#pragma unroll
                for (int r = 0; r < 4; r++)
                    theta_t[(pixb + cc * 64 + lg * 4 + r) * 16 + l15] =
                        f2b(acc[cc][csl][r]);
        } else if (cs == 1) {     // phi pool
#pragma unroll
            for (int h2 = 0; h2 < 2; h2++) {
                float m = max4(acc[0][csl][2 * h2], acc[0][csl][2 * h2 + 1],
                               acc[1][csl][2 * h2], acc[1][csl][2 * h2 + 1]);
                int j = rp * 32 + h * 16 + p * 8 + lg * 2 + h2;
                phi_t[((size_t)b * 1024 + j) * 16 + l15] = f2b(m);
            }
        } else {                  // g pool, blocked layout
            int gcrow = (cs - 2) * 16 + l15;
            float m0 = max4(acc[0][csl][0], acc[0][csl][1], acc[1][csl][0], acc[1][csl][1]);
            float m1 = max4(acc[0][csl][2], acc[0][csl][3], acc[1][csl][2], acc[1][csl][3]);
            int jb = rp * 2 + h, jl = p * 8 + lg * 2;
            *(int*)(g_blk + (((size_t)b * 64 + jb) * 64 + gcrow) * 16 + jl) = cvtpk(m0, m1);
        }
    }
}

// ---------------------------------------------------------------------------
// K2: attention. Block = (b, 32 i's) -> 1024 blocks. Wave w = j-quarter.
// VALU-diet version: SHIFT folded into MFMA C-init, v_cvt_pk_bf16_f32 for all
// bf16 packing, v_permlane32_swap_b32 for the lane-half exchange (removes
// X[16]/Xo[16] and all cndmask selection). Data movement is bit-identical to
// the shfl_xor version: swap(W[c],W[c+2]) -> (lam?X[c+2]:W[c], lam?W[c+2]:X[c]).
__global__ __launch_bounds__(256) void attn_k(
    const float* __restrict__ x, const short* __restrict__ theta_t,
    const short* __restrict__ phi_t, const short* __restrict__ g_blk,
    const short* __restrict__ wo_b, const float* __restrict__ gamma_p,
    float* __restrict__ out)
{
    __shared__ float lds[4 * 2 * 16 * 64 + 4 * 64];   // 32 KB partials + 1 KB l
    const int tid = threadIdx.x;
    const int w = tid >> 6, lane = tid & 63, l31 = lane & 31, lam = lane >> 5;
    const int b = blockIdx.x >> 7, i0 = (blockIdx.x & 127) << 5;
    const int i = i0 + l31;

    // persistent theta B-frag: B[n=i][k=c], k = lam*8+q (K=16 exact)
    short8 tb = *(const short8*)(theta_t + ((size_t)b * 4096 + i) * 16 + lam * 8);

    f32x16 acc0, acc1, z16;
#pragma unroll
    for (int r = 0; r < 16; r++) { acc0[r] = 0.f; acc1[r] = 0.f; z16[r] = -SHIFT; }
    float rs = 0.f;

    for (int t = 0; t < 4; t++) {
        const int jt = w * 4 + t;
        // ---- QK: S^T[64j][32i] - SHIFT, rows j = jk*32 + (reg&3)+8*(reg>>2)+4*lam
        f32x16 s0, s1;
        {
            short8 pa0 = *(const short8*)(phi_t + ((size_t)b * 1024 + jt * 64 + l31) * 16 + lam * 8);
            short8 pa1 = *(const short8*)(phi_t + ((size_t)b * 1024 + jt * 64 + 32 + l31) * 16 + lam * 8);
            s0 = MFMA32(pa0, tb, z16, 0, 0, 0);
            s1 = MFMA32(pa1, tb, z16, 0, 0, 0);
        }
        // ---- exp + pack pairs: W[jk*8+rg*2+h] covers j = 32jk+8rg+4lam+2h+{0,1}
        int W[16];
#pragma unroll
        for (int jk = 0; jk < 2; jk++)
#pragma unroll
            for (int rg = 0; rg < 4; rg++)
#pragma unroll
                for (int h = 0; h < 2; h++) {
                    float p0 = __expf((jk ? s1 : s0)[rg * 4 + 2 * h]);
                    float p1 = __expf((jk ? s1 : s0)[rg * 4 + 2 * h + 1]);
                    rs += p0 + p1;
                    W[jk * 8 + rg * 2 + h] = cvtpk(p0, p1);
                }

        // ---- PV: O^T[c][i] += G^T . P^T ; B-frag via permlane32_swap pairs
#pragma unroll
        for (int ck = 0; ck < 4; ck++) {
            const int cb2 = (ck >> 1) * 8 + (ck & 1) * 4;
            int a0 = W[cb2], a1 = W[cb2 + 1], a2 = W[cb2 + 2], a3 = W[cb2 + 3];
            plswap(a0, a2);   // a0 = lam? partner W[c+2] : own W[c]; a2 = other half
            plswap(a1, a3);
            int4v pi; pi.x = a0; pi.y = a1; pi.z = a2; pi.w = a3;
            short8 pb = __builtin_bit_cast(short8, pi);
            const short* gp = g_blk + (((size_t)b * 64 + jt * 4 + ck) * 64) * 16;
            short8 ga0 = *(const short8*)(gp + (l31)      * 16 + lam * 8);
            short8 ga1 = *(const short8*)(gp + (32 + l31) * 16 + lam * 8);
            acc0 = MFMA32(ga0, pb, acc0, 0, 0, 0);
            acc1 = MFMA32(ga1, pb, acc1, 0, 0, 0);
        }
    }

    // ---- combine lane halves of row-sum (both halves hold same i=l31)
    rs += __shfl_xor(rs, 32, 64);

    // ---- write partials, one barrier, 4-way j-quarter combine
#pragma unroll
    for (int reg = 0; reg < 16; reg++) {
        lds[((w * 2 + 0) * 16 + reg) * 64 + lane] = acc0[reg];
        lds[((w * 2 + 1) * 16 + reg) * 64 + lane] = acc1[reg];
    }
    lds[8192 + w * 64 + lane] = rs;
    __syncthreads();

    float o[32];
#pragma unroll
    for (int cs2 = 0; cs2 < 2; cs2++)
#pragma unroll
        for (int reg = 0; reg < 16; reg++)
            o[cs2 * 16 + reg] =
                (lds[((0 * 2 + cs2) * 16 + reg) * 64 + lane] +
                 lds[((1 * 2 + cs2) * 16 + reg) * 64 + lane]) +
                (lds[((2 * 2 + cs2) * 16 + reg) * 64 + lane] +
                 lds[((3 * 2 + cs2) * 16 + reg) * 64 + lane]);
    float lf = (lds[8192 + 0 * 64 + lane] + lds[8192 + 1 * 64 + lane]) +
               (lds[8192 + 2 * 64 + lane] + lds[8192 + 3 * 64 + lane]);
    float rinv = 1.0f / lf;
#pragma unroll
    for (int k = 0; k < 32; k++) o[k] *= rinv;

    // pack O^T rows c = cs2*32 + 8rg + 4lam + 2h+{0,1}
    int Wo[16];
#pragma unroll
    for (int cs2 = 0; cs2 < 2; cs2++)
#pragma unroll
        for (int rg = 0; rg < 4; rg++)
#pragma unroll
            for (int h = 0; h < 2; h++)
                Wo[cs2 * 8 + rg * 2 + h] =
                    cvtpk(o[cs2 * 16 + rg * 4 + 2 * h], o[cs2 * 16 + rg * 4 + 2 * h + 1]);

    // ---- w_o GEMM: wave w owns co slice [w*32, w*32+32)
    const float gam = gamma_p[0];
    f32x16 oc;
#pragma unroll
    for (int r = 0; r < 16; r++) oc[r] = 0.f;
#pragma unroll
    for (int kc = 0; kc < 4; kc++) {
        const int cb2 = (kc >> 1) * 8 + (kc & 1) * 4;
        int a0 = Wo[cb2], a1 = Wo[cb2 + 1], a2 = Wo[cb2 + 2], a3 = Wo[cb2 + 3];
        plswap(a0, a2);
        plswap(a1, a3);
        int4v pi; pi.x = a0; pi.y = a1; pi.z = a2; pi.w = a3;
        short8 ob = __builtin_bit_cast(short8, pi);
        short8 wa = *(const short8*)(wo_b + (size_t)(w * 32 + l31) * 64 + kc * 16 + lam * 8);
        oc = MFMA32(wa, ob, oc, 0, 0, 0);
    }
#pragma unroll
    for (int reg = 0; reg < 16; reg++) {
        int co = w * 32 + (reg & 3) + 8 * (reg >> 2) + 4 * lam;
        size_t idx = ((size_t)b * 128 + co) * HW + i0 + l31;
        out[idx] = gam * oc[reg] + x[idx];
    }
}

// ---------------------------------------------------------------------------
extern "C" void kernel_launch(void* const* d_in, const int* in_sizes, int n_in,
                              void* d_out, int out_size, void* d_ws, size_t ws_size,
                              hipStream_t stream)
{
    const float* x     = (const float*)d_in[0];
    const float* wt    = (const float*)d_in[1];
    const float* wp    = (const float*)d_in[2];
    const float* wg    = (const float*)d_in[3];
    const float* wo    = (const float*)d_in[4];
    const float* gamma = (const float*)d_in[5];
    float* out = (float*)d_out;

    char* ws = (char*)d_ws;
    short* theta_t = (short*)(ws + 0);        // 8*4096*16 sh = 1048576 B
    short* phi_t   = (short*)(ws + 1048576);  // 8*1024*16 sh = 262144 B
    short* g_blk   = (short*)(ws + 1310720);  // 8*64*64*16 sh = 1048576 B
    short* wb      = (short*)(ws + 2359296);  // 20480 sh = 40960 B bf16 weights

    wconv    <<<20,   256, 0, stream>>>(wt, wp, wg, wo, wb);
    conv_pool<<<512,  256, 0, stream>>>(x, wb, theta_t, phi_t, g_blk);
    attn_k   <<<1024, 256, 0, stream>>>(x, theta_t, phi_t, g_blk, wb + 12288, gamma, out);
}